// Round 13
// baseline (432.558 us; speedup 1.0000x reference)
//
#include <hip/hip_runtime.h>
#include <hip/hip_bf16.h>
#include <stdint.h>

#define BATCH_N 65536
#define KDIM 1024
#define NTOT 1536

typedef __bf16 bf16x8 __attribute__((ext_vector_type(8)));
typedef float f32x4 __attribute__((ext_vector_type(4)));

__device__ __forceinline__ unsigned short f2bf(float f) {
    unsigned u = __builtin_bit_cast(unsigned, f);
    u += 0x7FFFu + ((u >> 16) & 1u);   // round-to-nearest-even
    return (unsigned short)(u >> 16);
}

// ---------------------------------------------------------------------------
// Kernel 1: x[b][k] = sum(node_memories[id]) + node_embedding[id][k], bf16,
// pre-swizzled (k ^= (b&7)<<3).  One WAVE per row; each lane owns 4 float4
// chunks at k = q*256 + lane*4, butterfly reduce.
// ---------------------------------------------------------------------------
__global__ __launch_bounds__(256) void prep_kernel(
    const int* __restrict__ ids,
    const float* __restrict__ mem,
    const float* __restrict__ emb,
    unsigned short* __restrict__ x)
{
    const int b    = blockIdx.x * 4 + (threadIdx.x >> 6);
    const int lane = threadIdx.x & 63;
    const int id   = ids[b];
    const float4* m4 = (const float4*)(mem + (size_t)id * KDIM) + lane;
    const float4* e4 = (const float4*)(emb + (size_t)id * KDIM) + lane;
    float4 v0 = m4[0];
    float4 v1 = m4[64];
    float4 v2 = m4[128];
    float4 v3 = m4[192];
    float s = (v0.x + v0.y + v0.z + v0.w) + (v1.x + v1.y + v1.z + v1.w)
            + (v2.x + v2.y + v2.z + v2.w) + (v3.x + v3.y + v3.z + v3.w);
    #pragma unroll
    for (int off = 1; off < 64; off <<= 1) s += __shfl_xor(s, off, 64);
    unsigned short* xb = x + (size_t)b * KDIM;
    #pragma unroll
    for (int q = 0; q < 4; ++q) {
        float4 e = e4[q * 64];
        ushort4 o;
        o.x = f2bf(s + e.x);
        o.y = f2bf(s + e.y);
        o.z = f2bf(s + e.z);
        o.w = f2bf(s + e.w);
        const int k   = q * 256 + lane * 4;
        const int ksw = k ^ ((b & 7) << 3);
        *(ushort4*)(xb + ksw) = o;
    }
}

// ---------------------------------------------------------------------------
// Kernel 2: Wt[n][k] = W_{n/512}[k][n%512] in bf16, same pre-swizzle on k.
// ---------------------------------------------------------------------------
__global__ __launch_bounds__(256) void wconv_kernel(
    const float* __restrict__ Wq, const float* __restrict__ Ws,
    const float* __restrict__ Wk, unsigned short* __restrict__ wt)
{
    const int gt = blockIdx.x * 256 + threadIdx.x;   // 0..393215
    const int n  = gt % NTOT;
    const int kb = (gt / NTOT) * 4;
    const float* W = (n < 512) ? Wq : ((n < 1024) ? Ws : Wk);
    const int nn = n & 511;
    ushort4 o;
    o.x = f2bf(W[(size_t)(kb + 0) * 512 + nn]);
    o.y = f2bf(W[(size_t)(kb + 1) * 512 + nn]);
    o.z = f2bf(W[(size_t)(kb + 2) * 512 + nn]);
    o.w = f2bf(W[(size_t)(kb + 3) * 512 + nn]);
    const int ksw = kb ^ ((n & 7) << 3);
    *(ushort4*)(wt + (size_t)n * KDIM + ksw) = o;
}

// ---------------------------------------------------------------------------
// Kernel 3: 256x256 GEMM, ONE barrier per K-tile, stage-early/wait-late.
//   Per tile t (slot s = t&1):
//     STG(slot s^1, tile t+1)   [8 DMA instrs, issued ~3000 cyc before use]
//     24 ds_read_b128 of slot s + 64 MFMA  [compiler-counted lgkm waits,
//        no intra-tile barriers: reads hit slot s, DMA writes slot s^1 --
//        disjoint, so phase barriers serve no hazard]
//     VM0 (free: DMA issued a full tile ago) ; BAR  (slot swap)
//   Ledger: RAW -- tile t+1 reads sit behind VM0+BAR, outstanding VMEM = 0
//   at every tile boundary.  WAR -- slot s^1's last readers (tile t-1) had
//   reads serviced before their MFMAs issued, which precede BAR(t-1), which
//   precedes this STG.  16 barriers/block total (vs 128 in r12).
// ---------------------------------------------------------------------------
#define BM 256
#define BN 256
#define BK 64
#define MT (BATCH_N / BM)   // 256
#define NT (NTOT / BN)      // 6
#define NWG (MT * NT)       // 1536 = 8 * 192, 192 % 6 == 0 -> bijective

#define BAR() asm volatile("s_barrier" ::: "memory")
#define VM0() asm volatile("s_waitcnt vmcnt(0)" ::: "memory")
#define AS1 __attribute__((address_space(1)))
#define AS3 __attribute__((address_space(3)))

__global__ __launch_bounds__(512, 2) void gemm_kernel(
    const unsigned short* __restrict__ X,    // [65536][1024] bf16, swizzled
    const unsigned short* __restrict__ Wt,   // [1536][1024]  bf16, swizzled
    const float* __restrict__ bq, const float* __restrict__ bs,
    const float* __restrict__ bk, float* __restrict__ out)
{
    __shared__ __align__(16) unsigned short sA[32768];   // 64 KiB
    __shared__ __align__(16) unsigned short sB[32768];   // 64 KiB

    const int tid  = threadIdx.x;
    const int xcd  = blockIdx.x & 7;
    const int idx  = blockIdx.x >> 3;
    const int wgid = xcd * (NWG / 8) + idx;
    const int nt   = wgid % NT;              // n fastest: A-panel L2 reuse
    const int mt   = wgid / NT;
    const int m0   = mt * BM;
    const int n0   = nt * BN;
    const int wid  = tid >> 6;
    const int lane = tid & 63;
    const int wm   = wid >> 2;               // 0..1
    const int wn   = wid & 3;                // 0..3
    const int r16  = lane & 15;
    const int kb0  = (lane >> 4) << 4;       // 0,16,32,48 (bytes)
    const int ksw  = (r16 & 7) << 4;         // LDS XOR swizzle (bytes)

    f32x4 acc[8][4];
    #pragma unroll
    for (int i = 0; i < 8; i++)
        #pragma unroll
        for (int j = 0; j < 4; j++)
            acc[i][j] = f32x4{0.f, 0.f, 0.f, 0.f};

    bf16x8 af0[4][2], af1[4][2], bfr0[2][2], bfr1[2][2];

    const unsigned short* gA = X  + (size_t)(m0 + (tid >> 3)) * KDIM + (tid & 7) * 8;
    const unsigned short* gB = Wt + (size_t)(n0 + (tid >> 3)) * KDIM + (tid & 7) * 8;
    const int ldst = (tid & 448) * 8;        // wave-uniform LDS elem offset

// stage ONE half-tile (2 DMA instrs/thread)
#define STG_A(slot, h, kt) do {                                                 \
    _Pragma("unroll")                                                            \
    for (int c = 0; c < 2; ++c)                                                  \
        __builtin_amdgcn_global_load_lds(                                        \
            (const AS1 void*)(gA + (size_t)((h) * 128 + c * 64) * KDIM + (kt) * BK), \
            (AS3 void*)(&sA[((slot) * 2 + (h)) * 8192 + c * 4096 + ldst]),       \
            16, 0, 0);                                                           \
} while (0)
#define STG_B(slot, h, kt) do {                                                 \
    _Pragma("unroll")                                                            \
    for (int c = 0; c < 2; ++c)                                                  \
        __builtin_amdgcn_global_load_lds(                                        \
            (const AS1 void*)(gB + (size_t)((h) * 128 + c * 64) * KDIM + (kt) * BK), \
            (AS3 void*)(&sB[((slot) * 2 + (h)) * 8192 + c * 4096 + ldst]),       \
            16, 0, 0);                                                           \
} while (0)

#define LDA(SET, slot, qa) do {                                                 \
    const char* p = (const char*)&sA[((slot) * 2 + (qa)) * 8192];                \
    _Pragma("unroll")                                                            \
    for (int i = 0; i < 4; ++i)                                                  \
        _Pragma("unroll")                                                        \
        for (int kk = 0; kk < 2; ++kk)                                           \
            SET[i][kk] = *(const bf16x8*)(p + (wm * 64 + i * 16 + r16) * 128     \
                                            + ((kk * 64 + kb0) ^ ksw));          \
} while (0)
#define LDB(SET, slot, qb) do {                                                 \
    const char* p = (const char*)&sB[((slot) * 2 + (qb)) * 8192];                \
    _Pragma("unroll")                                                            \
    for (int j = 0; j < 2; ++j)                                                  \
        _Pragma("unroll")                                                        \
        for (int kk = 0; kk < 2; ++kk)                                           \
            SET[j][kk] = *(const bf16x8*)(p + (wn * 32 + j * 16 + r16) * 128     \
                                            + ((kk * 64 + kb0) ^ ksw));          \
} while (0)

#define MM(QA, QB, ASET, BSET) do {                                             \
    __builtin_amdgcn_s_setprio(1);                                               \
    _Pragma("unroll")                                                            \
    for (int i = 0; i < 4; ++i)                                                  \
        _Pragma("unroll")                                                        \
        for (int j = 0; j < 2; ++j)                                              \
            _Pragma("unroll")                                                    \
            for (int kk = 0; kk < 2; ++kk)                                       \
                acc[(QA) * 4 + i][(QB) * 2 + j] =                                \
                    __builtin_amdgcn_mfma_f32_16x16x32_bf16(                     \
                        ASET[i][kk], BSET[j][kk],                                \
                        acc[(QA) * 4 + i][(QB) * 2 + j], 0, 0, 0);               \
    __builtin_amdgcn_s_setprio(0);                                               \
} while (0)

// one K-tile: stage next tile into other slot, read+compute this slot,
// VM0 (free), barrier.
#define TILE(S, NS, KTN, DOSTAGE) do {                                          \
    if (DOSTAGE) {                                                               \
        STG_A(NS, 0, KTN); STG_A(NS, 1, KTN);                                    \
        STG_B(NS, 0, KTN); STG_B(NS, 1, KTN);                                    \
    }                                                                            \
    LDA(af0, S, 0); LDB(bfr0, S, 0);                                             \
    LDA(af1, S, 1); LDB(bfr1, S, 1);                                             \
    MM(0, 0, af0, bfr0); MM(0, 1, af0, bfr1);                                    \
    MM(1, 1, af1, bfr1); MM(1, 0, af1, bfr0);                                    \
    VM0(); BAR();                                                                \
} while (0)

    // ---- prologue: stage tile0 into slot0 ----
    STG_A(0, 0, 0); STG_A(0, 1, 0); STG_B(0, 0, 0); STG_B(0, 1, 0);
    VM0();
    BAR();

    // ---- main loop: tiles 0..13 (stage t+1), tails 14 (stage 15), 15 ----
    #pragma unroll 1
    for (int t = 0; t < 7; ++t) {
        TILE(0, 1, 2 * t + 1, 1);
        TILE(1, 0, 2 * t + 2, 1);
    }
    TILE(0, 1, 15, 1);
    TILE(1, 0, 0, 0);

    // ---- epilogue: bias + sigmoid, nontemporal fp32 stores ----
    // C/D layout: col=lane&15, row=(lane>>4)*4+reg  [m89/m91]
    const int grp = nt >> 1;                        // 0=q, 1=s, 2=k
    const float* bias = (grp == 0) ? bq : ((grp == 1) ? bs : bk);
    float* obase = out + (size_t)grp * ((size_t)BATCH_N * 512);
    const int cb = (nt & 1) * 256;
    #pragma unroll
    for (int qb = 0; qb < 2; ++qb)
        #pragma unroll
        for (int j = 0; j < 2; ++j) {
            const int col = cb + qb * 128 + wn * 32 + j * 16 + r16;
            const float bv = bias[col];
            #pragma unroll
            for (int qa = 0; qa < 2; ++qa)
                #pragma unroll
                for (int i = 0; i < 4; ++i) {
                    const int rbase = m0 + qa * 128 + wm * 64 + i * 16 + ((lane >> 4) << 2);
                    #pragma unroll
                    for (int r = 0; r < 4; ++r) {
                        float v = acc[qa * 4 + i][qb * 2 + j][r] + bv;
                        v = 1.0f / (1.0f + __expf(-v));
                        __builtin_nontemporal_store(v, &obase[(size_t)(rbase + r) * 512 + col]);
                    }
                }
        }
#undef STG_A
#undef STG_B
#undef LDA
#undef LDB
#undef MM
#undef TILE
}

extern "C" void kernel_launch(void* const* d_in, const int* in_sizes, int n_in,
                              void* d_out, int out_size, void* d_ws, size_t ws_size,
                              hipStream_t stream) {
    const int*   ids = (const int*)d_in[0];
    const float* mem = (const float*)d_in[1];
    const float* emb = (const float*)d_in[2];
    const float* Wq  = (const float*)d_in[3];
    const float* bq  = (const float*)d_in[4];
    const float* Ws  = (const float*)d_in[5];
    const float* bs  = (const float*)d_in[6];
    const float* Wk  = (const float*)d_in[7];
    const float* bk  = (const float*)d_in[8];
    float* out = (float*)d_out;

    unsigned short* x  = (unsigned short*)d_ws;              // 65536*1024 bf16 = 128 MiB
    unsigned short* wt = x + (size_t)BATCH_N * KDIM;         // 1536*1024  bf16 = 3 MiB

    hipLaunchKernelGGL(wconv_kernel, dim3(NTOT), dim3(256), 0, stream, Wq, Ws, Wk, wt);
    hipLaunchKernelGGL(prep_kernel, dim3(BATCH_N / 4), dim3(256), 0, stream, ids, mem, emb, x);
    hipLaunchKernelGGL(gemm_kernel, dim3(NWG), dim3(512), 0, stream,
                       x, wt, bq, bs, bk, out);
}

// Round 14
// 394.587 us; speedup vs baseline: 1.0962x; 1.0962x over previous
//
#include <hip/hip_runtime.h>
#include <hip/hip_bf16.h>
#include <stdint.h>

#define BATCH_N 65536
#define KDIM 1024
#define NTOT 1536

typedef __bf16 bf16x8 __attribute__((ext_vector_type(8)));
typedef float f32x4 __attribute__((ext_vector_type(4)));

__device__ __forceinline__ unsigned short f2bf(float f) {
    unsigned u = __builtin_bit_cast(unsigned, f);
    u += 0x7FFFu + ((u >> 16) & 1u);   // round-to-nearest-even
    return (unsigned short)(u >> 16);
}

// ---------------------------------------------------------------------------
// Kernel 1: x[b][k] = sum(node_memories[id]) + node_embedding[id][k], bf16,
// pre-swizzled (k ^= (b&7)<<3).  One WAVE per row; each lane owns 4 float4
// chunks at k = q*256 + lane*4, butterfly reduce.
// ---------------------------------------------------------------------------
__global__ __launch_bounds__(256) void prep_kernel(
    const int* __restrict__ ids,
    const float* __restrict__ mem,
    const float* __restrict__ emb,
    unsigned short* __restrict__ x)
{
    const int b    = blockIdx.x * 4 + (threadIdx.x >> 6);
    const int lane = threadIdx.x & 63;
    const int id   = ids[b];
    const float4* m4 = (const float4*)(mem + (size_t)id * KDIM) + lane;
    const float4* e4 = (const float4*)(emb + (size_t)id * KDIM) + lane;
    float4 v0 = m4[0];
    float4 v1 = m4[64];
    float4 v2 = m4[128];
    float4 v3 = m4[192];
    float s = (v0.x + v0.y + v0.z + v0.w) + (v1.x + v1.y + v1.z + v1.w)
            + (v2.x + v2.y + v2.z + v2.w) + (v3.x + v3.y + v3.z + v3.w);
    #pragma unroll
    for (int off = 1; off < 64; off <<= 1) s += __shfl_xor(s, off, 64);
    unsigned short* xb = x + (size_t)b * KDIM;
    #pragma unroll
    for (int q = 0; q < 4; ++q) {
        float4 e = e4[q * 64];
        ushort4 o;
        o.x = f2bf(s + e.x);
        o.y = f2bf(s + e.y);
        o.z = f2bf(s + e.z);
        o.w = f2bf(s + e.w);
        const int k   = q * 256 + lane * 4;
        const int ksw = k ^ ((b & 7) << 3);
        *(ushort4*)(xb + ksw) = o;
    }
}

// ---------------------------------------------------------------------------
// Kernel 2: Wt[n][k] = W_{n/512}[k][n%512] in bf16, same pre-swizzle on k.
// ---------------------------------------------------------------------------
__global__ __launch_bounds__(256) void wconv_kernel(
    const float* __restrict__ Wq, const float* __restrict__ Ws,
    const float* __restrict__ Wk, unsigned short* __restrict__ wt)
{
    const int gt = blockIdx.x * 256 + threadIdx.x;   // 0..393215
    const int n  = gt % NTOT;
    const int kb = (gt / NTOT) * 4;
    const float* W = (n < 512) ? Wq : ((n < 1024) ? Ws : Wk);
    const int nn = n & 511;
    ushort4 o;
    o.x = f2bf(W[(size_t)(kb + 0) * 512 + nn]);
    o.y = f2bf(W[(size_t)(kb + 1) * 512 + nn]);
    o.z = f2bf(W[(size_t)(kb + 2) * 512 + nn]);
    o.w = f2bf(W[(size_t)(kb + 3) * 512 + nn]);
    const int ksw = kb ^ ((n & 7) << 3);
    *(ushort4*)(wt + (size_t)n * KDIM + ksw) = o;
}

// ---------------------------------------------------------------------------
// Kernel 3: 256x256 8-phase GEMM, FULL one-phase read-ahead (derived waits).
//   Per K-tile pair (even tile e=2t in s0, odd o=2t+1 in s1):
//     P1: MM(0,0)e      rd bfr1(s0q1)        STG B10(s1,ka)          BAR
//     P2: MM(0,1)e      rd af1(s0q1)         STG A00(s0,kb)          BAR
//     P3: MM(1,1)e                           STG B01(s0,kb)   VM4    BAR
//     P4: MM(1,0)e      rd af0,bfr0(s1q0)    STG A01(s0,kb)          BAR
//     P5: MM(0,0)o      rd bfr1(s1q1)        STG B00(s0,kb)          BAR
//     P6: MM(0,1)o      rd af1(s1q1)         STG A10(s1,kc)          BAR
//     P7: MM(1,1)o                           STG B11(s1,kc)   VM4    BAR
//     P8: MM(1,0)o      rd af0,bfr0(s0q0)    STG A11(s1,kc)          BAR
//   Every MM's operands are read exactly one phase earlier -> no lgkm stall
//   at MFMA issue (compiler-counted waits, reads serviced during prev phase).
//   VM4 at P3: newest-4 = {P2,P3} -> retires P1 + prev{P6,P7,P8} = tile o's
//   4 half-tiles; s1 reads open at P4 (post BAR, race-safe per r11 rule).
//   VM4 at P7: newest-4 = {P6,P7} -> retires P2..P5 = tile kb's half-tiles;
//   s0 reads open at P8.  Counted waits only, never 0 mid-loop.
//   WAR: every stage's region had its last ds_read serviced before the
//   preceding phase's MFMA issued (register dep) -> >=1 barrier separation.
// ---------------------------------------------------------------------------
#define BM 256
#define BN 256
#define BK 64
#define MT (BATCH_N / BM)   // 256
#define NT (NTOT / BN)      // 6
#define NWG (MT * NT)       // 1536 = 8 * 192, 192 % 6 == 0 -> bijective

#define BAR() asm volatile("s_barrier" ::: "memory")
#define VM4() asm volatile("s_waitcnt vmcnt(4)" ::: "memory")
#define VM0() asm volatile("s_waitcnt vmcnt(0)" ::: "memory")
#define AS1 __attribute__((address_space(1)))
#define AS3 __attribute__((address_space(3)))

__global__ __launch_bounds__(512, 2) void gemm_kernel(
    const unsigned short* __restrict__ X,    // [65536][1024] bf16, swizzled
    const unsigned short* __restrict__ Wt,   // [1536][1024]  bf16, swizzled
    const float* __restrict__ bq, const float* __restrict__ bs,
    const float* __restrict__ bk, float* __restrict__ out)
{
    __shared__ __align__(16) unsigned short sA[32768];   // 64 KiB
    __shared__ __align__(16) unsigned short sB[32768];   // 64 KiB

    const int tid  = threadIdx.x;
    const int xcd  = blockIdx.x & 7;
    const int idx  = blockIdx.x >> 3;
    const int wgid = xcd * (NWG / 8) + idx;
    const int nt   = wgid % NT;              // n fastest: A-panel L2 reuse
    const int mt   = wgid / NT;
    const int m0   = mt * BM;
    const int n0   = nt * BN;
    const int wid  = tid >> 6;
    const int lane = tid & 63;
    const int wm   = wid >> 2;               // 0..1
    const int wn   = wid & 3;                // 0..3
    const int r16  = lane & 15;
    const int kb0  = (lane >> 4) << 4;       // 0,16,32,48 (bytes)
    const int ksw  = (r16 & 7) << 4;         // LDS XOR swizzle (bytes)

    f32x4 acc[8][4];
    #pragma unroll
    for (int i = 0; i < 8; i++)
        #pragma unroll
        for (int j = 0; j < 4; j++)
            acc[i][j] = f32x4{0.f, 0.f, 0.f, 0.f};

    bf16x8 af0[4][2], af1[4][2], bfr0[2][2], bfr1[2][2];

    const unsigned short* gA = X  + (size_t)(m0 + (tid >> 3)) * KDIM + (tid & 7) * 8;
    const unsigned short* gB = Wt + (size_t)(n0 + (tid >> 3)) * KDIM + (tid & 7) * 8;
    const int ldst = (tid & 448) * 8;        // wave-uniform LDS elem offset

// stage ONE half-tile (2 DMA instrs/thread)
#define STG_A(slot, h, kt) do {                                                 \
    _Pragma("unroll")                                                            \
    for (int c = 0; c < 2; ++c)                                                  \
        __builtin_amdgcn_global_load_lds(                                        \
            (const AS1 void*)(gA + (size_t)((h) * 128 + c * 64) * KDIM + (kt) * BK), \
            (AS3 void*)(&sA[((slot) * 2 + (h)) * 8192 + c * 4096 + ldst]),       \
            16, 0, 0);                                                           \
} while (0)
#define STG_B(slot, h, kt) do {                                                 \
    _Pragma("unroll")                                                            \
    for (int c = 0; c < 2; ++c)                                                  \
        __builtin_amdgcn_global_load_lds(                                        \
            (const AS1 void*)(gB + (size_t)((h) * 128 + c * 64) * KDIM + (kt) * BK), \
            (AS3 void*)(&sB[((slot) * 2 + (h)) * 8192 + c * 4096 + ldst]),       \
            16, 0, 0);                                                           \
} while (0)

#define LDA(SET, slot, qa) do {                                                 \
    const char* p = (const char*)&sA[((slot) * 2 + (qa)) * 8192];                \
    _Pragma("unroll")                                                            \
    for (int i = 0; i < 4; ++i)                                                  \
        _Pragma("unroll")                                                        \
        for (int kk = 0; kk < 2; ++kk)                                           \
            SET[i][kk] = *(const bf16x8*)(p + (wm * 64 + i * 16 + r16) * 128     \
                                            + ((kk * 64 + kb0) ^ ksw));          \
} while (0)
#define LDB(SET, slot, qb) do {                                                 \
    const char* p = (const char*)&sB[((slot) * 2 + (qb)) * 8192];                \
    _Pragma("unroll")                                                            \
    for (int j = 0; j < 2; ++j)                                                  \
        _Pragma("unroll")                                                        \
        for (int kk = 0; kk < 2; ++kk)                                           \
            SET[j][kk] = *(const bf16x8*)(p + (wn * 32 + j * 16 + r16) * 128     \
                                            + ((kk * 64 + kb0) ^ ksw));          \
} while (0)

#define MM(QA, QB, ASET, BSET) do {                                             \
    __builtin_amdgcn_s_setprio(1);                                               \
    _Pragma("unroll")                                                            \
    for (int i = 0; i < 4; ++i)                                                  \
        _Pragma("unroll")                                                        \
        for (int j = 0; j < 2; ++j)                                              \
            _Pragma("unroll")                                                    \
            for (int kk = 0; kk < 2; ++kk)                                       \
                acc[(QA) * 4 + i][(QB) * 2 + j] =                                \
                    __builtin_amdgcn_mfma_f32_16x16x32_bf16(                     \
                        ASET[i][kk], BSET[j][kk],                                \
                        acc[(QA) * 4 + i][(QB) * 2 + j], 0, 0, 0);               \
    __builtin_amdgcn_s_setprio(0);                                               \
} while (0)

    // ---- prologue: tile0 full (s0) + tile1 {Ah0,Bh1,Ah1} (s1) ----
    STG_A(0, 0, 0); STG_A(0, 1, 0); STG_B(0, 0, 0); STG_B(0, 1, 0);
    STG_A(1, 0, 1); STG_B(1, 1, 1); STG_A(1, 1, 1);
    VM0();
    BAR();
    LDA(af0, 0, 0); LDB(bfr0, 0, 0);         // operands for P1's MM

    // ---- main loop: 7 iterations, tiles (2t in s0, 2t+1 in s1) ----
    #pragma unroll 1
    for (int t = 0; t < 7; ++t) {
        const int ka = 2 * t + 1, kb2 = 2 * t + 2, kc = 2 * t + 3;
        // P1
        MM(0, 0, af0, bfr0);
        LDB(bfr1, 0, 1); STG_B(1, 0, ka);                        BAR();
        // P2
        MM(0, 1, af0, bfr1);
        LDA(af1, 0, 1); STG_A(0, 0, kb2);                        BAR();
        // P3
        MM(1, 1, af1, bfr1); STG_B(0, 1, kb2); VM4();            BAR();
        // P4  (s1/tile-ka reads: safe behind P3's VM4+BAR)
        MM(1, 0, af1, bfr0);
        LDA(af0, 1, 0); LDB(bfr0, 1, 0); STG_A(0, 1, kb2);       BAR();
        // P5
        MM(0, 0, af0, bfr0);
        LDB(bfr1, 1, 1); STG_B(0, 0, kb2);                       BAR();
        // P6
        MM(0, 1, af0, bfr1);
        LDA(af1, 1, 1); STG_A(1, 0, kc);                         BAR();
        // P7
        MM(1, 1, af1, bfr1); STG_B(1, 1, kc); VM4();             BAR();
        // P8  (s0/tile-kb2 reads: safe behind P7's VM4+BAR)
        MM(1, 0, af1, bfr0);
        LDA(af0, 0, 0); LDB(bfr0, 0, 0); STG_A(1, 1, kc);        BAR();
    }
    // ---- tail: tiles 14 (s0), 15 (s1) ----
    // T1
    MM(0, 0, af0, bfr0);
    LDB(bfr1, 0, 1); STG_B(1, 0, 15);                            BAR();
    // T2
    MM(0, 1, af0, bfr1); LDA(af1, 0, 1);                         BAR();
    // T3
    MM(1, 1, af1, bfr1); VM0();                                  BAR();
    // T4
    MM(1, 0, af1, bfr0); LDA(af0, 1, 0); LDB(bfr0, 1, 0);        BAR();
    // T5
    MM(0, 0, af0, bfr0); LDB(bfr1, 1, 1);                        BAR();
    // T6
    MM(0, 1, af0, bfr1); LDA(af1, 1, 1);                         BAR();
    // T7
    MM(1, 1, af1, bfr1);                                         BAR();
    // T8
    MM(1, 0, af1, bfr0);

    // ---- epilogue: bias + sigmoid, nontemporal fp32 stores ----
    // C/D layout: col=lane&15, row=(lane>>4)*4+reg  [m89/m91]
    const int grp = nt >> 1;                        // 0=q, 1=s, 2=k
    const float* bias = (grp == 0) ? bq : ((grp == 1) ? bs : bk);
    float* obase = out + (size_t)grp * ((size_t)BATCH_N * 512);
    const int cb = (nt & 1) * 256;
    #pragma unroll
    for (int qb = 0; qb < 2; ++qb)
        #pragma unroll
        for (int j = 0; j < 2; ++j) {
            const int col = cb + qb * 128 + wn * 32 + j * 16 + r16;
            const float bv = bias[col];
            #pragma unroll
            for (int qa = 0; qa < 2; ++qa)
                #pragma unroll
                for (int i = 0; i < 4; ++i) {
                    const int rbase = m0 + qa * 128 + wm * 64 + i * 16 + ((lane >> 4) << 2);
                    #pragma unroll
                    for (int r = 0; r < 4; ++r) {
                        float v = acc[qa * 4 + i][qb * 2 + j][r] + bv;
                        v = 1.0f / (1.0f + __expf(-v));
                        __builtin_nontemporal_store(v, &obase[(size_t)(rbase + r) * 512 + col]);
                    }
                }
        }
#undef STG_A
#undef STG_B
#undef LDA
#undef LDB
#undef MM
}

extern "C" void kernel_launch(void* const* d_in, const int* in_sizes, int n_in,
                              void* d_out, int out_size, void* d_ws, size_t ws_size,
                              hipStream_t stream) {
    const int*   ids = (const int*)d_in[0];
    const float* mem = (const float*)d_in[1];
    const float* emb = (const float*)d_in[2];
    const float* Wq  = (const float*)d_in[3];
    const float* bq  = (const float*)d_in[4];
    const float* Ws  = (const float*)d_in[5];
    const float* bs  = (const float*)d_in[6];
    const float* Wk  = (const float*)d_in[7];
    const float* bk  = (const float*)d_in[8];
    float* out = (float*)d_out;

    unsigned short* x  = (unsigned short*)d_ws;              // 65536*1024 bf16 = 128 MiB
    unsigned short* wt = x + (size_t)BATCH_N * KDIM;         // 1536*1024  bf16 = 3 MiB

    hipLaunchKernelGGL(wconv_kernel, dim3(NTOT), dim3(256), 0, stream, Wq, Ws, Wk, wt);
    hipLaunchKernelGGL(prep_kernel, dim3(BATCH_N / 4), dim3(256), 0, stream, ids, mem, emb, x);
    hipLaunchKernelGGL(gemm_kernel, dim3(NWG), dim3(512), 0, stream,
                       x, wt, bq, bs, bk, out);
}